// Round 8
// baseline (280.655 us; speedup 1.0000x reference)
//
#include <hip/hip_runtime.h>
#include <cstdint>
#include <cmath>

#define KDIM    1024
#define DPROJ   4384
#define NPAD    4480   // 4384 padded to 35*128
#define CONVDIM 2304
#define SEQ     2048
#define BATCH   2
#define MROWS   4096   // BATCH*SEQ
#define NHEADS  32
#define HEADDIM 64
#define DSTATE  128
#define CHUNK   256
#define NCHUNK  8
#define DINNER  2048
#define EPS     1e-5f
#define LOG2E   1.44269504088896f

typedef unsigned short u16;
typedef float  f32x4  __attribute__((ext_vector_type(4)));
typedef __bf16 bf16x8 __attribute__((ext_vector_type(8)));
typedef u16    u16x8  __attribute__((ext_vector_type(8)));
typedef u16    u16x4  __attribute__((ext_vector_type(4)));

__device__ __forceinline__ u16 f2bf(float f){
  unsigned u = __builtin_bit_cast(unsigned, f);
  u += 0x7fffu + ((u >> 16) & 1u);   // RNE
  return (u16)(u >> 16);
}
__device__ __forceinline__ float bf2f(u16 s){
  unsigned u = ((unsigned)s) << 16;
  return __builtin_bit_cast(float, u);
}
__device__ __forceinline__ void gl_lds16(const void* g, void* l){
  __builtin_amdgcn_global_load_lds((const __attribute__((address_space(1))) void*)g,
                                   (__attribute__((address_space(3))) void*)l, 16, 0, 0);
}
__device__ __forceinline__ float sigmoidf_(float x){ return 1.f / (1.f + expf(-x)); }

// ---------------- fp32 -> bf16 conversion (u and W merged) ----------------
__global__ __launch_bounds__(256) void k_cvt(const float* __restrict__ u_in, u16* __restrict__ u_out,
                                             const float* __restrict__ w_in, u16* __restrict__ w_out){
  int bid = blockIdx.x;
  const float* in; u16* out; size_t i; int wpath = 0;
  if(bid < 4096){ in = u_in; out = u_out; i = ((size_t)bid * 256 + threadIdx.x) * 4; }
  else          { in = w_in; out = w_out; i = ((size_t)(bid - 4096) * 256 + threadIdx.x) * 4; wpath = 1; }
  float4 v = make_float4(0.f,0.f,0.f,0.f);
  if(!wpath || (int)(i >> 10) < DPROJ) v = *(const float4*)(in + i);
  unsigned a = (unsigned)f2bf(v.x) | ((unsigned)f2bf(v.y) << 16);
  unsigned b = (unsigned)f2bf(v.z) | ((unsigned)f2bf(v.w) << 16);
  uint2 o; o.x = a; o.y = b;
  *(uint2*)(out + i) = o;
}

// ---------------- in-projection GEMM: zq = bf16(u @ W^T), BK=64, XOR-swizzled LDS ----------------
// K-loop LDS swizzle (bank-conflict-free) as R5; vectorized LDS-transposed epilogue.
__global__ __launch_bounds__(256) void k_gemm(const u16* __restrict__ A, const u16* __restrict__ B,
                                              u16* __restrict__ zq, float* __restrict__ dtraw){
  __shared__ u16 smem[128*64*2];
  u16* As = smem;
  u16* Bs = smem + 128*64;
  int tid = threadIdx.x;
  int gid = blockIdx.x;
  int xcd = gid & 7, idx = gid >> 3;          // round-robin block->XCD
  int xm = xcd >> 2, xn = xcd & 3;            // 2 x 4 XCD regions
  int mblk = xm*16 + (idx & 15);
  int nblk = xn*9  + (idx >> 4);
  if(nblk >= 35) return;                      // padded region (uniform exit, pre-barrier)
  int m0 = mblk * 128, n0 = nblk * 128;
  int w = tid >> 6, lane = tid & 63, r = lane & 15, q = lane >> 4;
  int wm = (w >> 1) * 64, wn = (w & 1) * 64;
  f32x4 acc[4][4] = {};
  int cg = (tid & 7) ^ ((tid >> 3) & 7);      // swizzled source chunk
  const u16* Ag = A + (size_t)(m0 + (tid >> 3)) * KDIM + cg * 8;
  const u16* Bg = B + (size_t)(n0 + (tid >> 3)) * KDIM + cg * 8;
  for(int kt = 0; kt < KDIM/64; kt++){
    int k0 = kt * 64;
    #pragma unroll
    for(int m = 0; m < 4; m++){
      gl_lds16(Ag + (size_t)m*32*KDIM + k0, &As[((size_t)m*256 + tid) * 8]);
      gl_lds16(Bg + (size_t)m*32*KDIM + k0, &Bs[((size_t)m*256 + tid) * 8]);
    }
    __syncthreads();
    #pragma unroll
    for(int ks = 0; ks < 2; ks++){
      int ca = ((ks*4 + q) ^ (r & 7)) * 8;    // swizzled chunk offset
      bf16x8 af[4], bfm[4];
      #pragma unroll
      for(int i = 0; i < 4; i++) af[i]  = *(const bf16x8*)&As[(wm + i*16 + r) * 64 + ca];
      #pragma unroll
      for(int j = 0; j < 4; j++) bfm[j] = *(const bf16x8*)&Bs[(wn + j*16 + r) * 64 + ca];
      #pragma unroll
      for(int i = 0; i < 4; i++)
        #pragma unroll
        for(int j = 0; j < 4; j++)
          acc[i][j] = __builtin_amdgcn_mfma_f32_16x16x32_bf16(af[i], bfm[j], acc[i][j], 0, 0, 0);
    }
    __syncthreads();
  }
  // dt columns in fp32, from registers (only the 32 nblk==34 blocks)
  if(nblk == 34){
    #pragma unroll
    for(int i = 0; i < 4; i++)
      #pragma unroll
      for(int j = 0; j < 4; j++)
        #pragma unroll
        for(int e = 0; e < 4; e++){
          int row = m0 + wm + i*16 + q*4 + e;
          int col = wn + j*16 + r;            // == global col - 4352
          dtraw[(size_t)row * 128 + col] = acc[i][j][e];
        }
  }
  // LDS-transposed vectorized store of zq
  u16* Cs = smem;                             // reuse 32 KB
  #pragma unroll
  for(int i = 0; i < 4; i++)
    #pragma unroll
    for(int e = 0; e < 4; e++){
      int row = wm + i*16 + q*4 + e;
      int sw = ((row >> 2) & 3) << 4;
      #pragma unroll
      for(int j = 0; j < 4; j++){
        int col = wn + j*16 + r;
        Cs[row*128 + (col ^ sw)] = f2bf(acc[i][j][e]);
      }
    }
  __syncthreads();
  #pragma unroll
  for(int it = 0; it < 8; it++){
    int row = it*16 + (tid >> 4);
    int c0 = (tid & 15) * 8;
    int sw = ((row >> 2) & 3) << 4;
    u16x8 v = *(const u16x8*)&Cs[row*128 + (c0 ^ sw)];
    *(u16x8*)(zq + (size_t)(m0 + row) * NPAD + n0 + c0) = v;
  }
}

// ---------------- conv1d + silu + split; 4 consecutive c per thread (coalesced) ----------------
__global__ __launch_bounds__(256) void k_conv(const u16* __restrict__ zq,
                                              const float* __restrict__ cw,
                                              const float* __restrict__ cb,
                                              u16* __restrict__ xq, u16* __restrict__ xqT,
                                              u16* __restrict__ Bq, u16* __restrict__ Cq){
  int c0 = blockIdx.x * 256;            // 9 c-tiles over CONVDIM (tile 8 == B|C)
  int l0 = blockIdx.y * 64;             // 32 l-tiles over SEQ
  int b  = blockIdx.z;
  int tid = threadIdx.x;
  int cbase = c0 + (tid & 63) * 4;      // 4 consecutive channels
  int lb = l0 + (tid >> 6) * 16;        // 16 rows
  float wt[4][4], bias[4];
  #pragma unroll
  for(int cc = 0; cc < 4; cc++){
    float4 wv = *(const float4*)(cw + (cbase + cc)*4);
    wt[cc][0]=wv.x; wt[cc][1]=wv.y; wt[cc][2]=wv.z; wt[cc][3]=wv.w;
    bias[cc] = cb[cbase + cc];
  }
  const u16* zrow = zq + (size_t)(b*SEQ) * NPAD + 2048 + cbase;
  float w0[4] = {}, w1[4] = {}, w2[4] = {};
  if(lb-3 >= 0){ u16x4 v = *(const u16x4*)(zrow + (size_t)(lb-3)*NPAD);
    #pragma unroll
    for(int cc=0;cc<4;cc++) w0[cc] = bf2f(v[cc]); }
  if(lb-2 >= 0){ u16x4 v = *(const u16x4*)(zrow + (size_t)(lb-2)*NPAD);
    #pragma unroll
    for(int cc=0;cc<4;cc++) w1[cc] = bf2f(v[cc]); }
  if(lb-1 >= 0){ u16x4 v = *(const u16x4*)(zrow + (size_t)(lb-1)*NPAD);
    #pragma unroll
    for(int cc=0;cc<4;cc++) w2[cc] = bf2f(v[cc]); }
  u16 vals[16][4];
  #pragma unroll
  for(int rr = 0; rr < 16; rr++){
    u16x4 v = *(const u16x4*)(zrow + (size_t)(lb+rr)*NPAD);
    #pragma unroll
    for(int cc = 0; cc < 4; cc++){
      float in3 = bf2f(v[cc]);
      float a = bias[cc] + w0[cc]*wt[cc][0] + w1[cc]*wt[cc][1] + w2[cc]*wt[cc][2] + in3*wt[cc][3];
      vals[rr][cc] = f2bf(a * sigmoidf_(a));
      w0[cc] = w1[cc]; w1[cc] = w2[cc]; w2[cc] = in3;
    }
  }
  if(blockIdx.x < 8){                   // x region
    #pragma unroll
    for(int rr = 0; rr < 16; rr++){
      u16x4 o; o[0]=vals[rr][0]; o[1]=vals[rr][1]; o[2]=vals[rr][2]; o[3]=vals[rr][3];
      *(u16x4*)(xq + (size_t)(b*SEQ + lb + rr) * DINNER + cbase) = o;
    }
    #pragma unroll
    for(int cc = 0; cc < 4; cc++){
      int c = cbase + cc;
      int h = c >> 6, p = c & 63;
      u16* dst = xqT + ((size_t)((b*32 + h)*64) + p) * SEQ + lb;
      u16x8 v0, v1;
      #pragma unroll
      for(int m = 0; m < 8; m++){ v0[m] = vals[m][cc]; v1[m] = vals[8+m][cc]; }
      *(u16x8*)dst = v0;
      *(u16x8*)(dst + 8) = v1;
    }
  } else {                              // B (cols 0..127) | C (cols 128..255)
    int col = cbase - 2048;
    u16* dst = (col < 128) ? Bq : Cq;
    int c4 = col & 127;
    #pragma unroll
    for(int rr = 0; rr < 16; rr++){
      u16x4 o; o[0]=vals[rr][0]; o[1]=vals[rr][1]; o[2]=vals[rr][2]; o[3]=vals[rr][3];
      *(u16x4*)(dst + (size_t)(b*SEQ + lb + rr) * 128 + c4) = o;
    }
  }
}

// ---------------- dt=softplus(dtraw+bias) + per-chunk cumsum of dt*A ----------------
__global__ __launch_bounds__(256) void k_acum(const float* __restrict__ dtraw,
                                              const float* __restrict__ dt_bias,
                                              const float* __restrict__ A_log,
                                              float* __restrict__ dtb,
                                              float* __restrict__ acum,
                                              float* __restrict__ cdec){
  int bid = blockIdx.x;               // (b*8+c)*32+h
  int h = bid & 31, c = (bid >> 5) & 7, b = bid >> 8;
  int t = threadIdx.x;
  __shared__ float sb[256];
  size_t row = (size_t)(b*SEQ + c*CHUNK + t);
  float v = dtraw[row * 128 + h] + dt_bias[h];
  float dt = (v > 20.f) ? v : log1pf(expf(v));
  dtb[row * 32 + h] = dt;
  float Ah = -expf(A_log[h]);
  float a = dt * Ah;
  sb[t] = a; __syncthreads();
  for(int off = 1; off < 256; off <<= 1){
    float vv = (t >= off) ? sb[t - off] : 0.f;
    __syncthreads();
    sb[t] += vv;
    __syncthreads();
  }
  float ac = sb[t];
  acum[(size_t)bid * 256 + t] = ac;
  if(t == 255) cdec[bid] = exp2f(ac * LOG2E);
}

// ---------------- chunk-final states (bf16 out): x^T global, decay*dt folded into B ----------------
__global__ __launch_bounds__(256) void k_states(const u16* __restrict__ xqT, const u16* __restrict__ Bq,
                                                const float* __restrict__ dtb,
                                                const float* __restrict__ acum,
                                                u16* __restrict__ states){
  int bid = blockIdx.x;               // (b*8+c)*32+h
  int h = bid & 31, c = (bid >> 5) & 7, b = bid >> 8;
  int tid = threadIdx.x;
  int w = tid >> 6, lane = tid & 63, r = lane & 15, q = lane >> 4;
  __shared__ u16 bT[128*72];          // [n][l], B * exp(alast-acum) * dt
  size_t rowB = (size_t)(b*SEQ + c*CHUNK);
  const u16* xrow = xqT + (size_t)((b*32 + h)*64) * SEQ + c*CHUNK;
  float alast = acum[(size_t)bid * 256 + 255];
  f32x4 acc[4][2] = {};
  for(int slab = 0; slab < 4; slab++){
    int lb = slab * 64;
    int l = lane;
    float f = exp2f((alast - acum[(size_t)bid * 256 + lb + l]) * LOG2E) * dtb[(rowB + lb + l) * 32 + h];
    __syncthreads();
    const u16* bp = Bq + (rowB + lb + l) * 128 + w*32;
    #pragma unroll
    for(int k = 0; k < 4; k++){
      u16x8 v = *(const u16x8*)(bp + k*8);
      #pragma unroll
      for(int m = 0; m < 8; m++)
        bT[(w*32 + k*8 + m)*72 + l] = f2bf(bf2f(v[m]) * f);
    }
    __syncthreads();
    #pragma unroll
    for(int ks = 0; ks < 2; ks++){
      bf16x8 af[4], bfr[2];
      #pragma unroll
      for(int i = 0; i < 4; i++)
        af[i] = *(const bf16x8*)&xrow[(size_t)(i*16 + r) * SEQ + lb + ks*32 + q*8];
      #pragma unroll
      for(int j = 0; j < 2; j++) bfr[j] = *(const bf16x8*)&bT[(w*32 + j*16 + r)*72 + ks*32 + q*8];
      #pragma unroll
      for(int i = 0; i < 4; i++)
        #pragma unroll
        for(int j = 0; j < 2; j++)
          acc[i][j] = __builtin_amdgcn_mfma_f32_16x16x32_bf16(af[i], bfr[j], acc[i][j], 0, 0, 0);
    }
  }
  #pragma unroll
  for(int i = 0; i < 4; i++)
    #pragma unroll
    for(int j = 0; j < 2; j++)
      #pragma unroll
      for(int e = 0; e < 4; e++){
        int p = i*16 + q*4 + e;
        int n = w*32 + j*16 + r;
        states[((size_t)bid * 64 + p) * 128 + n] = f2bf(acc[i][j][e]);
      }
}

// ---------------- inter-chunk sequential scan (bf16 in, bf16 prev out) ----------------
__global__ __launch_bounds__(256) void k_scan(const u16* __restrict__ states,
                                              const float* __restrict__ cdec,
                                              u16* __restrict__ prevb){
  size_t i = (size_t)blockIdx.x * 256 + threadIdx.x;
  int n = (int)(i & 127), p = (int)((i >> 7) & 63), h = (int)((i >> 13) & 31), b = (int)(i >> 18);
  float carry = 0.f;
  for(int c = 0; c < NCHUNK; c++){
    int bch = (b*8 + c)*32 + h;
    size_t off = ((size_t)bch * 64 + p) * 128 + n;
    float s = bf2f(states[off]);
    prevb[off] = f2bf(carry);
    carry = carry * cdec[bch] + s;
  }
}

// ---------------- Y = Y_off + Y_diag (bf16 out); ONE WAVE per (bch, 32-row l-tile) ----------------
// grid 4096 single-wave blocks. Zero barriers. G is local-row indexed [0,32).
__global__ __launch_bounds__(64) void k_y(const u16* __restrict__ xqT, const u16* __restrict__ Bq,
                                          const u16* __restrict__ Cq, const float* __restrict__ dtb,
                                          const float* __restrict__ acum, const u16* __restrict__ prevb,
                                          u16* __restrict__ yq){
  int bid = blockIdx.x;                 // bch*8 + lt8
  int lt8 = bid & 7, bch = bid >> 3;
  int h = bch & 31, c = (bch >> 5) & 7, b = bch >> 8;
  int t = threadIdx.x, r = t & 15, q = t >> 4;
  int l0 = lt8 * 32;
  __shared__ float acl2[256];
  __shared__ float dts[256];
  __shared__ u16 G[32*72];
  size_t rowC = (size_t)(b*SEQ + c*CHUNK);
  #pragma unroll
  for(int it = 0; it < 4; it++){
    int s = it*64 + t;
    acl2[s] = acum[(size_t)bch * 256 + s] * LOG2E;
    dts[s] = dtb[(rowC + s) * 32 + h];
  }
  // C fragments (2 row-groups of 16)
  bf16x8 cf[2][4];
  #pragma unroll
  for(int i = 0; i < 2; i++)
    #pragma unroll
    for(int ks = 0; ks < 4; ks++)
      cf[i][ks] = *(const bf16x8*)&Cq[(rowC + l0 + i*16 + r) * 128 + ks*32 + q*8];
  // Y_off = C . prev^T
  f32x4 accY[2][4] = {};
  #pragma unroll
  for(int ks = 0; ks < 4; ks++){
    #pragma unroll
    for(int j = 0; j < 4; j++){
      bf16x8 bfr = *(const bf16x8*)&prevb[((size_t)bch * 64 + j*16 + r) * 128 + ks*32 + q*8];
      #pragma unroll
      for(int i = 0; i < 2; i++)
        accY[i][j] = __builtin_amdgcn_mfma_f32_16x16x32_bf16(cf[i][ks], bfr, accY[i][j], 0, 0, 0);
    }
  }
  #pragma unroll
  for(int i = 0; i < 2; i++)
    #pragma unroll
    for(int e = 0; e < 4; e++){
      float sc = exp2f(acl2[l0 + i*16 + q*4 + e]);
      #pragma unroll
      for(int j = 0; j < 4; j++) accY[i][j][e] *= sc;
    }
  // diagonal s-tiles
  const u16* xrow = xqT + (size_t)((b*32 + h)*64) * SEQ + c*CHUNK;
  int ntile = (lt8 >> 1) + 1;
  for(int st = 0; st < ntile; st++){
    int s0 = st * 64;
    f32x4 accS[2][4] = {};
    #pragma unroll
    for(int ks = 0; ks < 4; ks++){
      #pragma unroll
      for(int j = 0; j < 4; j++){
        bf16x8 bfr = *(const bf16x8*)&Bq[(rowC + s0 + j*16 + r) * 128 + ks*32 + q*8];
        #pragma unroll
        for(int i = 0; i < 2; i++)
          accS[i][j] = __builtin_amdgcn_mfma_f32_16x16x32_bf16(cf[i][ks], bfr, accS[i][j], 0, 0, 0);
      }
    }
    float aS[4], dS[4];
    #pragma unroll
    for(int j = 0; j < 4; j++){ aS[j] = acl2[s0 + j*16 + r]; dS[j] = dts[s0 + j*16 + r]; }
    if(st < ntile - 1){                  // strictly-below: no mask
      #pragma unroll
      for(int i = 0; i < 2; i++)
        #pragma unroll
        for(int e = 0; e < 4; e++){
          float aL = acl2[l0 + i*16 + q*4 + e];
          #pragma unroll
          for(int j = 0; j < 4; j++){
            float v = accS[i][j][e] * exp2f(aL - aS[j]) * dS[j];
            G[(i*16 + q*4 + e)*72 + j*16 + r] = f2bf(v);
          }
        }
    } else {                             // diagonal tile: causal mask
      #pragma unroll
      for(int i = 0; i < 2; i++)
        #pragma unroll
        for(int e = 0; e < 4; e++){
          int lr = i*16 + q*4 + e;       // local row [0,32)
          int ll = l0 + lr;
          float aL = acl2[ll];
          #pragma unroll
          for(int j = 0; j < 4; j++){
            int ss = s0 + j*16 + r;
            float v = (ll >= ss) ? accS[i][j][e] * exp2f(aL - aS[j]) * dS[j] : 0.f;
            G[lr*72 + j*16 + r] = f2bf(v);
          }
        }
    }
    #pragma unroll
    for(int ks = 0; ks < 2; ks++){
      bf16x8 gf[2], xf[4];
      #pragma unroll
      for(int i = 0; i < 2; i++) gf[i] = *(const bf16x8*)&G[(i*16 + r)*72 + ks*32 + q*8];
      #pragma unroll
      for(int j = 0; j < 4; j++)
        xf[j] = *(const bf16x8*)&xrow[(size_t)(j*16 + r) * SEQ + s0 + ks*32 + q*8];
      #pragma unroll
      for(int i = 0; i < 2; i++)
        #pragma unroll
        for(int j = 0; j < 4; j++)
          accY[i][j] = __builtin_amdgcn_mfma_f32_16x16x32_bf16(gf[i], xf[j], accY[i][j], 0, 0, 0);
    }
  }
  #pragma unroll
  for(int i = 0; i < 2; i++)
    #pragma unroll
    for(int j = 0; j < 4; j++)
      #pragma unroll
      for(int e = 0; e < 4; e++){
        int ll = l0 + i*16 + q*4 + e;
        int p = j*16 + r;
        yq[(rowC + ll) * (size_t)DINNER + h*64 + p] = f2bf(accY[i][j][e]);
      }
}

// ---------------- gated RMSNorm + D*x fold, fp32 output ----------------
__global__ __launch_bounds__(256) void k_norm(const u16* __restrict__ yq, const u16* __restrict__ xq,
                                              const u16* __restrict__ zq, const float* __restrict__ Dp,
                                              const float* __restrict__ nw, float* __restrict__ out){
  int bl = blockIdx.x;
  int t = threadIdx.x;
  float Dh = Dp[t >> 3];                 // 8 cols per thread, 64 cols per head
  u16x8 yv = *(const u16x8*)(yq + (size_t)bl * DINNER + t*8);
  u16x8 xv = *(const u16x8*)(xq + (size_t)bl * DINNER + t*8);
  u16x8 zv = *(const u16x8*)(zq + (size_t)bl * NPAD + t*8);
  float g[8];
  float ss = 0.f;
  #pragma unroll
  for(int m = 0; m < 8; m++){
    float y = bf2f(yv[m]) + Dh * bf2f(xv[m]);
    float z = bf2f(zv[m]);
    float v = y * (z * sigmoidf_(z));
    g[m] = v;
    ss += v * v;
  }
  #pragma unroll
  for(int off = 32; off > 0; off >>= 1) ss += __shfl_down(ss, off, 64);
  __shared__ float wsum[4];
  if((t & 63) == 0) wsum[t >> 6] = ss;
  __syncthreads();
  float tot = wsum[0] + wsum[1] + wsum[2] + wsum[3];
  float scale = rsqrtf(tot / (float)DINNER + EPS);
  float4 o0, o1;
  o0.x = g[0]*scale*nw[t*8+0]; o0.y = g[1]*scale*nw[t*8+1];
  o0.z = g[2]*scale*nw[t*8+2]; o0.w = g[3]*scale*nw[t*8+3];
  o1.x = g[4]*scale*nw[t*8+4]; o1.y = g[5]*scale*nw[t*8+5];
  o1.z = g[6]*scale*nw[t*8+6]; o1.w = g[7]*scale*nw[t*8+7];
  *(float4*)(out + (size_t)bl * DINNER + t*8)     = o0;
  *(float4*)(out + (size_t)bl * DINNER + t*8 + 4) = o1;
}

extern "C" void kernel_launch(void* const* d_in, const int* in_sizes, int n_in,
                              void* d_out, int out_size, void* d_ws, size_t ws_size,
                              hipStream_t stream){
  const float* u    = (const float*)d_in[0];
  const float* W    = (const float*)d_in[1];
  const float* cw   = (const float*)d_in[2];
  const float* cb   = (const float*)d_in[3];
  const float* dtbi = (const float*)d_in[4];
  const float* Alog = (const float*)d_in[5];
  const float* Dp   = (const float*)d_in[6];
  const float* nw   = (const float*)d_in[7];
  float* out = (float*)d_out;

  char* ws = (char*)d_ws;
  size_t off = 0;
  auto alloc = [&](size_t bytes) -> void* {
    void* p = ws + off;
    off += (bytes + 255) & ~(size_t)255;
    return p;
  };
  u16*   u_bf    = (u16*)  alloc((size_t)MROWS * KDIM * 2);        //  8.4 MB
  u16*   W_bf    = (u16*)  alloc((size_t)NPAD * KDIM * 2);         //  9.2 MB
  u16*   zq      = (u16*)  alloc((size_t)MROWS * NPAD * 2);        // 36.7 MB
  float* dtraw   = (float*)alloc((size_t)MROWS * 128 * 4);         //  2.1 MB
  u16*   xq      = (u16*)  alloc((size_t)MROWS * DINNER * 2);      // 16.8 MB
  u16*   xqT     = (u16*)  alloc((size_t)MROWS * DINNER * 2);      // 16.8 MB
  u16*   Bq      = (u16*)  alloc((size_t)MROWS * 128 * 2);         //  1.0 MB
  u16*   Cq      = (u16*)  alloc((size_t)MROWS * 128 * 2);         //  1.0 MB
  float* dtb     = (float*)alloc((size_t)MROWS * 32 * 4);          //  0.5 MB
  float* acum    = (float*)alloc((size_t)512 * 256 * 4);           //  0.5 MB
  float* cdec    = (float*)alloc((size_t)512 * 4);
  u16*   states  = (u16*)  alloc((size_t)512 * 64 * 128 * 2);      //  8.4 MB
  u16*   prevb   = (u16*)  alloc((size_t)512 * 64 * 128 * 2);      //  8.4 MB
  u16*   yq      = (u16*)  alloc((size_t)MROWS * DINNER * 2);      // 16.8 MB

  k_cvt<<<4096 + 4480, 256, 0, stream>>>(u, u_bf, W, W_bf);
  k_gemm<<<1152, 256, 0, stream>>>(u_bf, W_bf, zq, dtraw);
  k_conv<<<dim3(9, 32, 2), 256, 0, stream>>>(zq, cw, cb, xq, xqT, Bq, Cq);
  k_acum<<<512, 256, 0, stream>>>(dtraw, dtbi, Alog, dtb, acum, cdec);
  k_states<<<512, 256, 0, stream>>>(xqT, Bq, dtb, acum, states);
  k_scan<<<((size_t)BATCH*NHEADS*64*128)/256, 256, 0, stream>>>(states, cdec, prevb);
  k_y<<<4096, 64, 0, stream>>>(xqT, Bq, Cq, dtb, acum, prevb, yq);
  k_norm<<<MROWS, 256, 0, stream>>>(yq, xq, zq, Dp, nw, out);
}

// Round 9
// 256.943 us; speedup vs baseline: 1.0923x; 1.0923x over previous
//
#include <hip/hip_runtime.h>
#include <cstdint>
#include <cmath>

#define KDIM    1024
#define DPROJ   4384
#define NPAD    4480   // 4384 padded to 35*128
#define CONVDIM 2304
#define SEQ     2048
#define BATCH   2
#define MROWS   4096   // BATCH*SEQ
#define NHEADS  32
#define HEADDIM 64
#define DSTATE  128
#define CHUNK   256
#define NCHUNK  8
#define DINNER  2048
#define EPS     1e-5f
#define LOG2E   1.44269504088896f

typedef unsigned short u16;
typedef float  f32x4  __attribute__((ext_vector_type(4)));
typedef __bf16 bf16x8 __attribute__((ext_vector_type(8)));
typedef u16    u16x8  __attribute__((ext_vector_type(8)));
typedef u16    u16x4  __attribute__((ext_vector_type(4)));

__device__ __forceinline__ u16 f2bf(float f){
  unsigned u = __builtin_bit_cast(unsigned, f);
  u += 0x7fffu + ((u >> 16) & 1u);   // RNE
  return (u16)(u >> 16);
}
__device__ __forceinline__ float bf2f(u16 s){
  unsigned u = ((unsigned)s) << 16;
  return __builtin_bit_cast(float, u);
}
__device__ __forceinline__ void gl_lds16(const void* g, void* l){
  __builtin_amdgcn_global_load_lds((const __attribute__((address_space(1))) void*)g,
                                   (__attribute__((address_space(3))) void*)l, 16, 0, 0);
}
__device__ __forceinline__ float sigmoidf_(float x){ return 1.f / (1.f + expf(-x)); }

// ---------------- fp32 -> bf16 conversion (u and W merged) ----------------
__global__ __launch_bounds__(256) void k_cvt(const float* __restrict__ u_in, u16* __restrict__ u_out,
                                             const float* __restrict__ w_in, u16* __restrict__ w_out){
  int bid = blockIdx.x;
  const float* in; u16* out; size_t i; int wpath = 0;
  if(bid < 4096){ in = u_in; out = u_out; i = ((size_t)bid * 256 + threadIdx.x) * 4; }
  else          { in = w_in; out = w_out; i = ((size_t)(bid - 4096) * 256 + threadIdx.x) * 4; wpath = 1; }
  float4 v = make_float4(0.f,0.f,0.f,0.f);
  if(!wpath || (int)(i >> 10) < DPROJ) v = *(const float4*)(in + i);
  unsigned a = (unsigned)f2bf(v.x) | ((unsigned)f2bf(v.y) << 16);
  unsigned b = (unsigned)f2bf(v.z) | ((unsigned)f2bf(v.w) << 16);
  uint2 o; o.x = a; o.y = b;
  *(uint2*)(out + i) = o;
}

// ---------------- in-projection GEMM: zq = bf16(u @ W^T), BK=64, XOR-swizzled LDS ----------------
__global__ __launch_bounds__(256) void k_gemm(const u16* __restrict__ A, const u16* __restrict__ B,
                                              u16* __restrict__ zq, float* __restrict__ dtraw){
  __shared__ u16 smem[128*64*2];
  u16* As = smem;
  u16* Bs = smem + 128*64;
  int tid = threadIdx.x;
  int gid = blockIdx.x;
  int xcd = gid & 7, idx = gid >> 3;          // round-robin block->XCD
  int xm = xcd >> 2, xn = xcd & 3;            // 2 x 4 XCD regions
  int mblk = xm*16 + (idx & 15);
  int nblk = xn*9  + (idx >> 4);
  if(nblk >= 35) return;                      // padded region (uniform exit, pre-barrier)
  int m0 = mblk * 128, n0 = nblk * 128;
  int w = tid >> 6, lane = tid & 63, r = lane & 15, q = lane >> 4;
  int wm = (w >> 1) * 64, wn = (w & 1) * 64;
  f32x4 acc[4][4] = {};
  int cg = (tid & 7) ^ ((tid >> 3) & 7);      // swizzled source chunk
  const u16* Ag = A + (size_t)(m0 + (tid >> 3)) * KDIM + cg * 8;
  const u16* Bg = B + (size_t)(n0 + (tid >> 3)) * KDIM + cg * 8;
  for(int kt = 0; kt < KDIM/64; kt++){
    int k0 = kt * 64;
    #pragma unroll
    for(int m = 0; m < 4; m++){
      gl_lds16(Ag + (size_t)m*32*KDIM + k0, &As[((size_t)m*256 + tid) * 8]);
      gl_lds16(Bg + (size_t)m*32*KDIM + k0, &Bs[((size_t)m*256 + tid) * 8]);
    }
    __syncthreads();
    #pragma unroll
    for(int ks = 0; ks < 2; ks++){
      int ca = ((ks*4 + q) ^ (r & 7)) * 8;    // swizzled chunk offset
      bf16x8 af[4], bfm[4];
      #pragma unroll
      for(int i = 0; i < 4; i++) af[i]  = *(const bf16x8*)&As[(wm + i*16 + r) * 64 + ca];
      #pragma unroll
      for(int j = 0; j < 4; j++) bfm[j] = *(const bf16x8*)&Bs[(wn + j*16 + r) * 64 + ca];
      #pragma unroll
      for(int i = 0; i < 4; i++)
        #pragma unroll
        for(int j = 0; j < 4; j++)
          acc[i][j] = __builtin_amdgcn_mfma_f32_16x16x32_bf16(af[i], bfm[j], acc[i][j], 0, 0, 0);
    }
    __syncthreads();
  }
  // dt columns in fp32, from registers (only the 32 nblk==34 blocks)
  if(nblk == 34){
    #pragma unroll
    for(int i = 0; i < 4; i++)
      #pragma unroll
      for(int j = 0; j < 4; j++)
        #pragma unroll
        for(int e = 0; e < 4; e++){
          int row = m0 + wm + i*16 + q*4 + e;
          int col = wn + j*16 + r;            // == global col - 4352
          dtraw[(size_t)row * 128 + col] = acc[i][j][e];
        }
  }
  // LDS-transposed vectorized store of zq
  u16* Cs = smem;                             // reuse 32 KB
  #pragma unroll
  for(int i = 0; i < 4; i++)
    #pragma unroll
    for(int e = 0; e < 4; e++){
      int row = wm + i*16 + q*4 + e;
      int sw = ((row >> 2) & 3) << 4;
      #pragma unroll
      for(int j = 0; j < 4; j++){
        int col = wn + j*16 + r;
        Cs[row*128 + (col ^ sw)] = f2bf(acc[i][j][e]);
      }
    }
  __syncthreads();
  #pragma unroll
  for(int it = 0; it < 8; it++){
    int row = it*16 + (tid >> 4);
    int c0 = (tid & 15) * 8;
    int sw = ((row >> 2) & 3) << 4;
    u16x8 v = *(const u16x8*)&Cs[row*128 + (c0 ^ sw)];
    *(u16x8*)(zq + (size_t)(m0 + row) * NPAD + n0 + c0) = v;
  }
}

// ---------------- conv1d + silu + split; 4 consecutive c per thread (coalesced) ----------------
__global__ __launch_bounds__(256) void k_conv(const u16* __restrict__ zq,
                                              const float* __restrict__ cw,
                                              const float* __restrict__ cb,
                                              u16* __restrict__ xq, u16* __restrict__ xqT,
                                              u16* __restrict__ Bq, u16* __restrict__ Cq){
  int c0 = blockIdx.x * 256;            // 9 c-tiles over CONVDIM (tile 8 == B|C)
  int l0 = blockIdx.y * 64;             // 32 l-tiles over SEQ
  int b  = blockIdx.z;
  int tid = threadIdx.x;
  int cbase = c0 + (tid & 63) * 4;      // 4 consecutive channels
  int lb = l0 + (tid >> 6) * 16;        // 16 rows
  float wt[4][4], bias[4];
  #pragma unroll
  for(int cc = 0; cc < 4; cc++){
    float4 wv = *(const float4*)(cw + (cbase + cc)*4);
    wt[cc][0]=wv.x; wt[cc][1]=wv.y; wt[cc][2]=wv.z; wt[cc][3]=wv.w;
    bias[cc] = cb[cbase + cc];
  }
  const u16* zrow = zq + (size_t)(b*SEQ) * NPAD + 2048 + cbase;
  float w0[4] = {}, w1[4] = {}, w2[4] = {};
  if(lb-3 >= 0){ u16x4 v = *(const u16x4*)(zrow + (size_t)(lb-3)*NPAD);
    #pragma unroll
    for(int cc=0;cc<4;cc++) w0[cc] = bf2f(v[cc]); }
  if(lb-2 >= 0){ u16x4 v = *(const u16x4*)(zrow + (size_t)(lb-2)*NPAD);
    #pragma unroll
    for(int cc=0;cc<4;cc++) w1[cc] = bf2f(v[cc]); }
  if(lb-1 >= 0){ u16x4 v = *(const u16x4*)(zrow + (size_t)(lb-1)*NPAD);
    #pragma unroll
    for(int cc=0;cc<4;cc++) w2[cc] = bf2f(v[cc]); }
  u16 vals[16][4];
  #pragma unroll
  for(int rr = 0; rr < 16; rr++){
    u16x4 v = *(const u16x4*)(zrow + (size_t)(lb+rr)*NPAD);
    #pragma unroll
    for(int cc = 0; cc < 4; cc++){
      float in3 = bf2f(v[cc]);
      float a = bias[cc] + w0[cc]*wt[cc][0] + w1[cc]*wt[cc][1] + w2[cc]*wt[cc][2] + in3*wt[cc][3];
      vals[rr][cc] = f2bf(a * sigmoidf_(a));
      w0[cc] = w1[cc]; w1[cc] = w2[cc]; w2[cc] = in3;
    }
  }
  if(blockIdx.x < 8){                   // x region
    #pragma unroll
    for(int rr = 0; rr < 16; rr++){
      u16x4 o; o[0]=vals[rr][0]; o[1]=vals[rr][1]; o[2]=vals[rr][2]; o[3]=vals[rr][3];
      *(u16x4*)(xq + (size_t)(b*SEQ + lb + rr) * DINNER + cbase) = o;
    }
    #pragma unroll
    for(int cc = 0; cc < 4; cc++){
      int c = cbase + cc;
      int h = c >> 6, p = c & 63;
      u16* dst = xqT + ((size_t)((b*32 + h)*64) + p) * SEQ + lb;
      u16x8 v0, v1;
      #pragma unroll
      for(int m = 0; m < 8; m++){ v0[m] = vals[m][cc]; v1[m] = vals[8+m][cc]; }
      *(u16x8*)dst = v0;
      *(u16x8*)(dst + 8) = v1;
    }
  } else {                              // B (cols 0..127) | C (cols 128..255)
    int col = cbase - 2048;
    u16* dst = (col < 128) ? Bq : Cq;
    int c4 = col & 127;
    #pragma unroll
    for(int rr = 0; rr < 16; rr++){
      u16x4 o; o[0]=vals[rr][0]; o[1]=vals[rr][1]; o[2]=vals[rr][2]; o[3]=vals[rr][3];
      *(u16x4*)(dst + (size_t)(b*SEQ + lb + rr) * 128 + c4) = o;
    }
  }
}

// ---------------- dt=softplus(dtraw+bias) + per-chunk cumsum of dt*A ----------------
__global__ __launch_bounds__(256) void k_acum(const float* __restrict__ dtraw,
                                              const float* __restrict__ dt_bias,
                                              const float* __restrict__ A_log,
                                              float* __restrict__ dtb,
                                              float* __restrict__ acum,
                                              float* __restrict__ cdec){
  int bid = blockIdx.x;               // (b*8+c)*32+h
  int h = bid & 31, c = (bid >> 5) & 7, b = bid >> 8;
  int t = threadIdx.x;
  __shared__ float sb[256];
  size_t row = (size_t)(b*SEQ + c*CHUNK + t);
  float v = dtraw[row * 128 + h] + dt_bias[h];
  float dt = (v > 20.f) ? v : log1pf(expf(v));
  dtb[row * 32 + h] = dt;
  float Ah = -expf(A_log[h]);
  float a = dt * Ah;
  sb[t] = a; __syncthreads();
  for(int off = 1; off < 256; off <<= 1){
    float vv = (t >= off) ? sb[t - off] : 0.f;
    __syncthreads();
    sb[t] += vv;
    __syncthreads();
  }
  float ac = sb[t];
  acum[(size_t)bid * 256 + t] = ac;
  if(t == 255) cdec[bid] = exp2f(ac * LOG2E);
}

// ---------------- chunk-final states (bf16 out): x^T global, decay*dt folded into B ----------------
__global__ __launch_bounds__(256) void k_states(const u16* __restrict__ xqT, const u16* __restrict__ Bq,
                                                const float* __restrict__ dtb,
                                                const float* __restrict__ acum,
                                                u16* __restrict__ states){
  int bid = blockIdx.x;               // (b*8+c)*32+h
  int h = bid & 31, c = (bid >> 5) & 7, b = bid >> 8;
  int tid = threadIdx.x;
  int w = tid >> 6, lane = tid & 63, r = lane & 15, q = lane >> 4;
  __shared__ u16 bT[128*72];          // [n][l], B * exp(alast-acum) * dt
  size_t rowB = (size_t)(b*SEQ + c*CHUNK);
  const u16* xrow = xqT + (size_t)((b*32 + h)*64) * SEQ + c*CHUNK;
  float alast = acum[(size_t)bid * 256 + 255];
  f32x4 acc[4][2] = {};
  for(int slab = 0; slab < 4; slab++){
    int lb = slab * 64;
    int l = lane;
    float f = exp2f((alast - acum[(size_t)bid * 256 + lb + l]) * LOG2E) * dtb[(rowB + lb + l) * 32 + h];
    __syncthreads();
    const u16* bp = Bq + (rowB + lb + l) * 128 + w*32;
    #pragma unroll
    for(int k = 0; k < 4; k++){
      u16x8 v = *(const u16x8*)(bp + k*8);
      #pragma unroll
      for(int m = 0; m < 8; m++)
        bT[(w*32 + k*8 + m)*72 + l] = f2bf(bf2f(v[m]) * f);
    }
    __syncthreads();
    #pragma unroll
    for(int ks = 0; ks < 2; ks++){
      bf16x8 af[4], bfr[2];
      #pragma unroll
      for(int i = 0; i < 4; i++)
        af[i] = *(const bf16x8*)&xrow[(size_t)(i*16 + r) * SEQ + lb + ks*32 + q*8];
      #pragma unroll
      for(int j = 0; j < 2; j++) bfr[j] = *(const bf16x8*)&bT[(w*32 + j*16 + r)*72 + ks*32 + q*8];
      #pragma unroll
      for(int i = 0; i < 4; i++)
        #pragma unroll
        for(int j = 0; j < 2; j++)
          acc[i][j] = __builtin_amdgcn_mfma_f32_16x16x32_bf16(af[i], bfr[j], acc[i][j], 0, 0, 0);
    }
  }
  #pragma unroll
  for(int i = 0; i < 4; i++)
    #pragma unroll
    for(int j = 0; j < 2; j++)
      #pragma unroll
      for(int e = 0; e < 4; e++){
        int p = i*16 + q*4 + e;
        int n = w*32 + j*16 + r;
        states[((size_t)bid * 64 + p) * 128 + n] = f2bf(acc[i][j][e]);
      }
}

// ---------------- inter-chunk sequential scan (bf16 in, bf16 prev out) ----------------
__global__ __launch_bounds__(256) void k_scan(const u16* __restrict__ states,
                                              const float* __restrict__ cdec,
                                              u16* __restrict__ prevb){
  size_t i = (size_t)blockIdx.x * 256 + threadIdx.x;
  int n = (int)(i & 127), p = (int)((i >> 7) & 63), h = (int)((i >> 13) & 31), b = (int)(i >> 18);
  float carry = 0.f;
  for(int c = 0; c < NCHUNK; c++){
    int bch = (b*8 + c)*32 + h;
    size_t off = ((size_t)bch * 64 + p) * 128 + n;
    float s = bf2f(states[off]);
    prevb[off] = f2bf(carry);
    carry = carry * cdec[bch] + s;
  }
}

// ---------------- Y = Y_off + Y_diag (bf16 out); one wave per (bch, 32-row l-tile) ----------------
// bid = lt8*512 + bch  ->  bid%8 == bch%8: all 8 l-tiles of a bch share an XCD (L2 reuse),
// same XCD k_states used for that head. Factorized decay for strictly-below tiles.
__global__ __launch_bounds__(64) void k_y(const u16* __restrict__ xqT, const u16* __restrict__ Bq,
                                          const u16* __restrict__ Cq, const float* __restrict__ dtb,
                                          const float* __restrict__ acum, const u16* __restrict__ prevb,
                                          u16* __restrict__ yq){
  int bid = blockIdx.x;
  int lt8 = bid >> 9, bch = bid & 511;
  int h = bch & 31, c = (bch >> 5) & 7, b = bch >> 8;
  int t = threadIdx.x, r = t & 15, q = t >> 4;
  int l0 = lt8 * 32;
  __shared__ float acl2[256];
  __shared__ float dts[256];
  __shared__ u16 G[32*72];
  size_t rowC = (size_t)(b*SEQ + c*CHUNK);
  #pragma unroll
  for(int it = 0; it < 4; it++){
    int s = it*64 + t;
    acl2[s] = acum[(size_t)bch * 256 + s] * LOG2E;
    dts[s] = dtb[(rowC + s) * 32 + h];
  }
  // C fragments (2 row-groups of 16)
  bf16x8 cf[2][4];
  #pragma unroll
  for(int i = 0; i < 2; i++)
    #pragma unroll
    for(int ks = 0; ks < 4; ks++)
      cf[i][ks] = *(const bf16x8*)&Cq[(rowC + l0 + i*16 + r) * 128 + ks*32 + q*8];
  // Y_off = C . prev^T
  f32x4 accY[2][4] = {};
  #pragma unroll
  for(int ks = 0; ks < 4; ks++){
    #pragma unroll
    for(int j = 0; j < 4; j++){
      bf16x8 bfr = *(const bf16x8*)&prevb[((size_t)bch * 64 + j*16 + r) * 128 + ks*32 + q*8];
      #pragma unroll
      for(int i = 0; i < 2; i++)
        accY[i][j] = __builtin_amdgcn_mfma_f32_16x16x32_bf16(cf[i][ks], bfr, accY[i][j], 0, 0, 0);
    }
  }
  float aref = acl2[l0];
  float rowf[2][4];                     // exp2(aL - aref) <= 1, reused by all below-tiles
  #pragma unroll
  for(int i = 0; i < 2; i++)
    #pragma unroll
    for(int e = 0; e < 4; e++){
      float aL = acl2[l0 + i*16 + q*4 + e];
      rowf[i][e] = exp2f(aL - aref);
      float sc = exp2f(aL);             // absolute decay for Y_off
      #pragma unroll
      for(int j = 0; j < 4; j++) accY[i][j][e] *= sc;
    }
  // diagonal s-tiles
  const u16* xrow = xqT + (size_t)((b*32 + h)*64) * SEQ + c*CHUNK;
  int ntile = (lt8 >> 1) + 1;
  for(int st = 0; st < ntile; st++){
    int s0 = st * 64;
    f32x4 accS[2][4] = {};
    #pragma unroll
    for(int ks = 0; ks < 4; ks++){
      #pragma unroll
      for(int j = 0; j < 4; j++){
        bf16x8 bfr = *(const bf16x8*)&Bq[(rowC + s0 + j*16 + r) * 128 + ks*32 + q*8];
        #pragma unroll
        for(int i = 0; i < 2; i++)
          accS[i][j] = __builtin_amdgcn_mfma_f32_16x16x32_bf16(cf[i][ks], bfr, accS[i][j], 0, 0, 0);
      }
    }
    float aS[4], dS[4];
    #pragma unroll
    for(int j = 0; j < 4; j++){ aS[j] = acl2[s0 + j*16 + r]; dS[j] = dts[s0 + j*16 + r]; }
    if(st < ntile - 1){                  // strictly-below: factorized decay, no mask
      float colf[4];
      #pragma unroll
      for(int j = 0; j < 4; j++) colf[j] = exp2f(aref - aS[j]) * dS[j];  // <= dt (s < l0)
      #pragma unroll
      for(int i = 0; i < 2; i++)
        #pragma unroll
        for(int e = 0; e < 4; e++){
          float rf = rowf[i][e];
          #pragma unroll
          for(int j = 0; j < 4; j++){
            float v = accS[i][j][e] * rf * colf[j];
            G[(i*16 + q*4 + e)*72 + j*16 + r] = f2bf(v);
          }
        }
    } else {                             // diagonal tile: causal mask, per-element decay
      #pragma unroll
      for(int i = 0; i < 2; i++)
        #pragma unroll
        for(int e = 0; e < 4; e++){
          int lr = i*16 + q*4 + e;       // local row [0,32)
          int ll = l0 + lr;
          float aL = acl2[ll];
          #pragma unroll
          for(int j = 0; j < 4; j++){
            int ss = s0 + j*16 + r;
            float v = (ll >= ss) ? accS[i][j][e] * exp2f(aL - aS[j]) * dS[j] : 0.f;
            G[lr*72 + j*16 + r] = f2bf(v);
          }
        }
    }
    #pragma unroll
    for(int ks = 0; ks < 2; ks++){
      bf16x8 gf[2], xf[4];
      #pragma unroll
      for(int i = 0; i < 2; i++) gf[i] = *(const bf16x8*)&G[(i*16 + r)*72 + ks*32 + q*8];
      #pragma unroll
      for(int j = 0; j < 4; j++)
        xf[j] = *(const bf16x8*)&xrow[(size_t)(j*16 + r) * SEQ + s0 + ks*32 + q*8];
      #pragma unroll
      for(int i = 0; i < 2; i++)
        #pragma unroll
        for(int j = 0; j < 4; j++)
          accY[i][j] = __builtin_amdgcn_mfma_f32_16x16x32_bf16(gf[i], xf[j], accY[i][j], 0, 0, 0);
    }
  }
  #pragma unroll
  for(int i = 0; i < 2; i++)
    #pragma unroll
    for(int j = 0; j < 4; j++)
      #pragma unroll
      for(int e = 0; e < 4; e++){
        int ll = l0 + i*16 + q*4 + e;
        int p = j*16 + r;
        yq[(rowC + ll) * (size_t)DINNER + h*64 + p] = f2bf(accY[i][j][e]);
      }
}

// ---------------- gated RMSNorm + D*x fold, fp32 output ----------------
__global__ __launch_bounds__(256) void k_norm(const u16* __restrict__ yq, const u16* __restrict__ xq,
                                              const u16* __restrict__ zq, const float* __restrict__ Dp,
                                              const float* __restrict__ nw, float* __restrict__ out){
  int bl = blockIdx.x;
  int t = threadIdx.x;
  float Dh = Dp[t >> 3];                 // 8 cols per thread, 64 cols per head
  u16x8 yv = *(const u16x8*)(yq + (size_t)bl * DINNER + t*8);
  u16x8 xv = *(const u16x8*)(xq + (size_t)bl * DINNER + t*8);
  u16x8 zv = *(const u16x8*)(zq + (size_t)bl * NPAD + t*8);
  float g[8];
  float ss = 0.f;
  #pragma unroll
  for(int m = 0; m < 8; m++){
    float y = bf2f(yv[m]) + Dh * bf2f(xv[m]);
    float z = bf2f(zv[m]);
    float v = y * (z * sigmoidf_(z));
    g[m] = v;
    ss += v * v;
  }
  #pragma unroll
  for(int off = 32; off > 0; off >>= 1) ss += __shfl_down(ss, off, 64);
  __shared__ float wsum[4];
  if((t & 63) == 0) wsum[t >> 6] = ss;
  __syncthreads();
  float tot = wsum[0] + wsum[1] + wsum[2] + wsum[3];
  float scale = rsqrtf(tot / (float)DINNER + EPS);
  float4 o0, o1;
  o0.x = g[0]*scale*nw[t*8+0]; o0.y = g[1]*scale*nw[t*8+1];
  o0.z = g[2]*scale*nw[t*8+2]; o0.w = g[3]*scale*nw[t*8+3];
  o1.x = g[4]*scale*nw[t*8+4]; o1.y = g[5]*scale*nw[t*8+5];
  o1.z = g[6]*scale*nw[t*8+6]; o1.w = g[7]*scale*nw[t*8+7];
  *(float4*)(out + (size_t)bl * DINNER + t*8)     = o0;
  *(float4*)(out + (size_t)bl * DINNER + t*8 + 4) = o1;
}

extern "C" void kernel_launch(void* const* d_in, const int* in_sizes, int n_in,
                              void* d_out, int out_size, void* d_ws, size_t ws_size,
                              hipStream_t stream){
  const float* u    = (const float*)d_in[0];
  const float* W    = (const float*)d_in[1];
  const float* cw   = (const float*)d_in[2];
  const float* cb   = (const float*)d_in[3];
  const float* dtbi = (const float*)d_in[4];
  const float* Alog = (const float*)d_in[5];
  const float* Dp   = (const float*)d_in[6];
  const float* nw   = (const float*)d_in[7];
  float* out = (float*)d_out;

  char* ws = (char*)d_ws;
  size_t off = 0;
  auto alloc = [&](size_t bytes) -> void* {
    void* p = ws + off;
    off += (bytes + 255) & ~(size_t)255;
    return p;
  };
  u16*   u_bf    = (u16*)  alloc((size_t)MROWS * KDIM * 2);        //  8.4 MB
  u16*   W_bf    = (u16*)  alloc((size_t)NPAD * KDIM * 2);         //  9.2 MB
  u16*   zq      = (u16*)  alloc((size_t)MROWS * NPAD * 2);        // 36.7 MB
  float* dtraw   = (float*)alloc((size_t)MROWS * 128 * 4);         //  2.1 MB
  u16*   xq      = (u16*)  alloc((size_t)MROWS * DINNER * 2);      // 16.8 MB
  u16*   xqT     = (u16*)  alloc((size_t)MROWS * DINNER * 2);      // 16.8 MB
  u16*   Bq      = (u16*)  alloc((size_t)MROWS * 128 * 2);         //  1.0 MB
  u16*   Cq      = (u16*)  alloc((size_t)MROWS * 128 * 2);         //  1.0 MB
  float* dtb     = (float*)alloc((size_t)MROWS * 32 * 4);          //  0.5 MB
  float* acum    = (float*)alloc((size_t)512 * 256 * 4);           //  0.5 MB
  float* cdec    = (float*)alloc((size_t)512 * 4);
  u16*   states  = (u16*)  alloc((size_t)512 * 64 * 128 * 2);      //  8.4 MB
  u16*   prevb   = (u16*)  alloc((size_t)512 * 64 * 128 * 2);      //  8.4 MB
  u16*   yq      = (u16*)  alloc((size_t)MROWS * DINNER * 2);      // 16.8 MB

  k_cvt<<<4096 + 4480, 256, 0, stream>>>(u, u_bf, W, W_bf);
  k_gemm<<<1152, 256, 0, stream>>>(u_bf, W_bf, zq, dtraw);
  k_conv<<<dim3(9, 32, 2), 256, 0, stream>>>(zq, cw, cb, xq, xqT, Bq, Cq);
  k_acum<<<512, 256, 0, stream>>>(dtraw, dtbi, Alog, dtb, acum, cdec);
  k_states<<<512, 256, 0, stream>>>(xqT, Bq, dtb, acum, states);
  k_scan<<<((size_t)BATCH*NHEADS*64*128)/256, 256, 0, stream>>>(states, cdec, prevb);
  k_y<<<4096, 64, 0, stream>>>(xqT, Bq, Cq, dtb, acum, prevb, yq);
  k_norm<<<MROWS, 256, 0, stream>>>(yq, xq, zq, Dp, nw, out);
}